// Round 1
// baseline (1232.475 us; speedup 1.0000x reference)
//
#include <hip/hip_runtime.h>

#define N_NODES 50000
#define N_EDGES 800000
#define CH 128
#define NOUT 10
#define NUM_GRAPHS 128
#define GEMM_ROWS 8

// ---------- degree / norm ----------
__global__ void k_init_deg(float* deg) {
    int i = blockIdx.x * blockDim.x + threadIdx.x;
    if (i < N_NODES) deg[i] = 1.0f;   // self-loop
}

__global__ void k_edge_deg(const int* __restrict__ dst, float* deg) {
    int e = blockIdx.x * blockDim.x + threadIdx.x;
    if (e < N_EDGES) atomicAdd(&deg[dst[e]], 1.0f);
}

__global__ void k_dinv(float* deg) {
    int i = blockIdx.x * blockDim.x + threadIdx.x;
    if (i < N_NODES) deg[i] = rsqrtf(deg[i]);   // deg >= 1 always
}

// ---------- zero fill ----------
__global__ void k_zero4(float4* p, int n4) {
    int i = blockIdx.x * blockDim.x + threadIdx.x;
    if (i < n4) p[i] = make_float4(0.f, 0.f, 0.f, 0.f);
}

// ---------- dense GEMM: Y[N,128] = X[N,128] @ W[128,128] ----------
__global__ __launch_bounds__(128) void k_gemm128(const float* __restrict__ X,
                                                 const float* __restrict__ W,
                                                 float* __restrict__ Y, int N) {
    __shared__ float xs[GEMM_ROWS][CH];
    const int row0 = blockIdx.x * GEMM_ROWS;
    const int c = threadIdx.x;
    #pragma unroll
    for (int r = 0; r < GEMM_ROWS; ++r) {
        int row = row0 + r;
        xs[r][c] = (row < N) ? X[(size_t)row * CH + c] : 0.0f;
    }
    __syncthreads();
    float acc[GEMM_ROWS] = {};
    #pragma unroll 4
    for (int k = 0; k < CH; ++k) {
        float w = W[k * CH + c];          // coalesced, L1-resident after first block
        #pragma unroll
        for (int r = 0; r < GEMM_ROWS; ++r) acc[r] += xs[r][k] * w;  // LDS broadcast
    }
    #pragma unroll
    for (int r = 0; r < GEMM_ROWS; ++r) {
        int row = row0 + r;
        if (row < N) Y[(size_t)row * CH + c] = acc[r];
    }
}

// ---------- scatter-aggregate: agg[v] += dinv[u]*dinv[v] * t[u] ----------
__global__ __launch_bounds__(256) void k_scatter(const int* __restrict__ src,
                                                 const int* __restrict__ dst,
                                                 const float* __restrict__ dinv,
                                                 const float* __restrict__ t,
                                                 float* __restrict__ agg) {
    int e = blockIdx.x * 2 + (threadIdx.x >> 7);
    int c = threadIdx.x & 127;
    if (e >= N_EDGES) return;
    int u = src[e], v = dst[e];
    float w = dinv[u] * dinv[v];
    atomicAdd(&agg[(size_t)v * CH + c], w * t[(size_t)u * CH + c]);
}

// ---------- finalize: h = relu(agg + dinv^2 * t + b) (in place in agg) ----------
__global__ void k_finalize(const float* __restrict__ t, float* __restrict__ agg,
                           const float* __restrict__ dinv, const float* __restrict__ b) {
    int idx = blockIdx.x * blockDim.x + threadIdx.x;
    if (idx >= N_NODES * CH) return;
    int v = idx >> 7, c = idx & 127;
    float d = dinv[v];
    float val = agg[idx] + d * d * t[idx] + b[c];
    agg[idx] = fmaxf(val, 0.0f);
}

// ---------- mean pool (atomic accumulate) ----------
__global__ void k_pool(const float* __restrict__ h, const int* __restrict__ batch,
                       float* __restrict__ psum, float* __restrict__ pcnt) {
    int idx = blockIdx.x * blockDim.x + threadIdx.x;
    if (idx >= N_NODES * CH) return;
    int v = idx >> 7, c = idx & 127;
    int g = batch[v];
    atomicAdd(&psum[g * CH + c], h[idx]);
    if (c == 0) atomicAdd(&pcnt[g], 1.0f);
}

// ---------- classifier head: out[g] = pooled[g] @ Wc + bc ----------
__global__ __launch_bounds__(128) void k_classify(const float* __restrict__ psum,
                                                  const float* __restrict__ pcnt,
                                                  const float* __restrict__ Wc,
                                                  const float* __restrict__ bc,
                                                  float* __restrict__ out) {
    __shared__ float p[CH];
    int g = blockIdx.x;
    int tid = threadIdx.x;
    float inv = 1.0f / fmaxf(pcnt[g], 1.0f);
    p[tid] = psum[g * CH + tid] * inv;
    __syncthreads();
    if (tid < NOUT) {
        float acc = bc[tid];
        #pragma unroll 4
        for (int k = 0; k < CH; ++k) acc += p[k] * Wc[k * NOUT + tid];
        out[g * NOUT + tid] = acc;
    }
}

extern "C" void kernel_launch(void* const* d_in, const int* in_sizes, int n_in,
                              void* d_out, int out_size, void* d_ws, size_t ws_size,
                              hipStream_t stream) {
    const float* x     = (const float*)d_in[0];
    const int*   ei    = (const int*)d_in[1];   // [2, E] row-major
    const int*   batch = (const int*)d_in[2];
    const float* W1    = (const float*)d_in[3];
    const float* b1    = (const float*)d_in[4];
    const float* W2    = (const float*)d_in[5];
    const float* b2    = (const float*)d_in[6];
    const float* Wc    = (const float*)d_in[7];
    const float* bc    = (const float*)d_in[8];
    float* out = (float*)d_out;

    const int* src = ei;
    const int* dst = ei + N_EDGES;

    float* dinv = (float*)d_ws;                       // N_NODES
    float* tbuf = dinv + N_NODES;                     // N*CH
    float* hbuf = tbuf + (size_t)N_NODES * CH;        // N*CH
    float* psum = hbuf + (size_t)N_NODES * CH;        // NUM_GRAPHS*CH
    float* pcnt = psum + NUM_GRAPHS * CH;             // NUM_GRAPHS

    const int NCH = N_NODES * CH;

    // degrees -> dinv (in place)
    k_init_deg<<<(N_NODES + 255) / 256, 256, 0, stream>>>(dinv);
    k_edge_deg<<<(N_EDGES + 255) / 256, 256, 0, stream>>>(dst, dinv);
    k_dinv<<<(N_NODES + 255) / 256, 256, 0, stream>>>(dinv);

    // ---- conv1 ----
    k_gemm128<<<(N_NODES + GEMM_ROWS - 1) / GEMM_ROWS, 128, 0, stream>>>(x, W1, tbuf, N_NODES);
    k_zero4<<<(NCH / 4 + 255) / 256, 256, 0, stream>>>((float4*)hbuf, NCH / 4);
    k_scatter<<<(N_EDGES + 1) / 2, 256, 0, stream>>>(src, dst, dinv, tbuf, hbuf);
    k_finalize<<<(NCH + 255) / 256, 256, 0, stream>>>(tbuf, hbuf, dinv, b1);

    // ---- conv2 ----
    k_gemm128<<<(N_NODES + GEMM_ROWS - 1) / GEMM_ROWS, 128, 0, stream>>>(hbuf, W2, tbuf, N_NODES);
    k_zero4<<<(NCH / 4 + 255) / 256, 256, 0, stream>>>((float4*)hbuf, NCH / 4);
    k_scatter<<<(N_EDGES + 1) / 2, 256, 0, stream>>>(src, dst, dinv, tbuf, hbuf);
    k_finalize<<<(NCH + 255) / 256, 256, 0, stream>>>(tbuf, hbuf, dinv, b2);

    // ---- pool + head ----
    k_zero4<<<((NUM_GRAPHS * CH + NUM_GRAPHS) / 4 + 255) / 256, 256, 0, stream>>>(
        (float4*)psum, (NUM_GRAPHS * CH + NUM_GRAPHS) / 4);
    k_pool<<<(NCH + 255) / 256, 256, 0, stream>>>(hbuf, batch, psum, pcnt);
    k_classify<<<NUM_GRAPHS, 128, 0, stream>>>(psum, pcnt, Wc, bc, out);
}

// Round 2
// 825.363 us; speedup vs baseline: 1.4933x; 1.4933x over previous
//
#include <hip/hip_runtime.h>

#define N_NODES 50000
#define N_EDGES 800000
#define CH 128
#define NOUT 10
#define NUM_GRAPHS 128
#define SCAN_B 256
#define N_SCAN_BLOCKS ((N_NODES + SCAN_B - 1) / SCAN_B)   // 196

// ---------- zero fills ----------
__global__ void k_zero_int(int* p, int n) {
    int i = blockIdx.x * blockDim.x + threadIdx.x;
    if (i < n) p[i] = 0;
}
__global__ void k_zero4(float4* p, int n4) {
    int i = blockIdx.x * blockDim.x + threadIdx.x;
    if (i < n4) p[i] = make_float4(0.f, 0.f, 0.f, 0.f);
}

// ---------- CSR build ----------
__global__ void k_hist(const int* __restrict__ dst, int* __restrict__ cnt) {
    int e = blockIdx.x * blockDim.x + threadIdx.x;
    if (e < N_EDGES) atomicAdd(&cnt[dst[e]], 1);
}

// block-level exclusive scan of cnt -> row_start (partial), block totals -> bsum
__global__ __launch_bounds__(SCAN_B) void k_scan1(const int* __restrict__ cnt,
                                                  int* __restrict__ row_start,
                                                  int* __restrict__ bsum) {
    __shared__ int s[SCAN_B];
    int tid = threadIdx.x;
    int i = blockIdx.x * SCAN_B + tid;
    int v = (i < N_NODES) ? cnt[i] : 0;
    s[tid] = v;
    __syncthreads();
    for (int off = 1; off < SCAN_B; off <<= 1) {
        int t = (tid >= off) ? s[tid - off] : 0;
        __syncthreads();
        s[tid] += t;
        __syncthreads();
    }
    if (i < N_NODES) row_start[i] = s[tid] - v;   // exclusive within block
    if (tid == SCAN_B - 1) bsum[blockIdx.x] = s[tid];
}

// single-block exclusive scan of block totals (in place)
__global__ __launch_bounds__(SCAN_B) void k_scan2(int* __restrict__ bsum) {
    __shared__ int s[SCAN_B];
    int tid = threadIdx.x;
    int v = (tid < N_SCAN_BLOCKS) ? bsum[tid] : 0;
    s[tid] = v;
    __syncthreads();
    for (int off = 1; off < SCAN_B; off <<= 1) {
        int t = (tid >= off) ? s[tid - off] : 0;
        __syncthreads();
        s[tid] += t;
        __syncthreads();
    }
    if (tid < N_SCAN_BLOCKS) bsum[tid] = s[tid] - v;  // exclusive
}

// add block offsets; init fill cursors; dinv = rsqrt(indeg + 1)
__global__ __launch_bounds__(SCAN_B) void k_scan3(int* __restrict__ row_start,
                                                  const int* __restrict__ bsum,
                                                  int* __restrict__ fill_pos,
                                                  const int* __restrict__ cnt,
                                                  float* __restrict__ dinv) {
    int i = blockIdx.x * SCAN_B + threadIdx.x;
    if (i < N_NODES) {
        int rs = row_start[i] + bsum[blockIdx.x];
        row_start[i] = rs;
        fill_pos[i] = rs;
        dinv[i] = rsqrtf((float)(cnt[i] + 1));   // +1 self-loop
    }
}

__global__ void k_fill(const int* __restrict__ src, const int* __restrict__ dst,
                       int* __restrict__ fill_pos, int* __restrict__ csr_src) {
    int e = blockIdx.x * blockDim.x + threadIdx.x;
    if (e < N_EDGES) {
        int pos = atomicAdd(&fill_pos[dst[e]], 1);
        csr_src[pos] = src[e];
    }
}

// ---------- dense GEMM: Y[N,128] = X[N,128] @ W[128,128] ----------
// block = 256 threads = 8 rows x 32 lanes; each thread: float4 of output.
// N_NODES % 8 == 0, so no bounds checks.
__global__ __launch_bounds__(256) void k_gemm128(const float* __restrict__ X,
                                                 const float* __restrict__ W,
                                                 float* __restrict__ Y) {
    __shared__ float xs[8][CH];
    const int tid = threadIdx.x;
    const int r = tid >> 5;
    const int lane = tid & 31;
    const int row0 = blockIdx.x * 8;

    // stage 8 rows of X (1024 floats) with 256 float4 loads
    ((float4*)xs)[tid] = ((const float4*)(X + (size_t)row0 * CH))[tid];
    __syncthreads();

    float4 acc = make_float4(0.f, 0.f, 0.f, 0.f);
    const float4* Wv = (const float4*)W;
    #pragma unroll 4
    for (int k = 0; k < CH; ++k) {
        float4 w = Wv[k * 32 + lane];   // coalesced; L1/L2-resident
        float xv = xs[r][k];            // LDS broadcast
        acc.x = fmaf(xv, w.x, acc.x);
        acc.y = fmaf(xv, w.y, acc.y);
        acc.z = fmaf(xv, w.z, acc.z);
        acc.w = fmaf(xv, w.w, acc.w);
    }
    ((float4*)(Y + (size_t)(row0 + r) * CH))[lane] = acc;
}

// ---------- CSR gather-aggregate + bias + relu ----------
// block = 256 = 8 node-groups x 32 lanes; each lane holds 4 channels (float4).
// h[v] = relu( dinv[v] * (sum_u dinv[u]*t[u] + dinv[v]*t[v]) + b )
__global__ __launch_bounds__(256) void k_gather(const float* __restrict__ t,
                                                const int* __restrict__ csr_src,
                                                const int* __restrict__ row_start,
                                                const int* __restrict__ cnt,
                                                const float* __restrict__ dinv,
                                                const float* __restrict__ b,
                                                float* __restrict__ h) {
    const int g = threadIdx.x >> 5;
    const int lane = threadIdx.x & 31;
    const int v = blockIdx.x * 8 + g;          // N_NODES % 8 == 0

    const int start = row_start[v];
    const int len = cnt[v];
    const float dv = dinv[v];
    const float4* tv = (const float4*)t;

    float4 self = tv[v * 32 + lane];
    float4 acc;
    acc.x = dv * self.x; acc.y = dv * self.y;
    acc.z = dv * self.z; acc.w = dv * self.w;

    for (int j = 0; j < len; ++j) {
        int u = csr_src[start + j];            // broadcast within group
        float w = dinv[u];
        float4 tu = tv[u * 32 + lane];         // 512B coalesced per group
        acc.x = fmaf(w, tu.x, acc.x);
        acc.y = fmaf(w, tu.y, acc.y);
        acc.z = fmaf(w, tu.z, acc.z);
        acc.w = fmaf(w, tu.w, acc.w);
    }

    float4 bb = ((const float4*)b)[lane];
    float4 o;
    o.x = fmaxf(fmaf(dv, acc.x, bb.x), 0.f);
    o.y = fmaxf(fmaf(dv, acc.y, bb.y), 0.f);
    o.z = fmaxf(fmaf(dv, acc.z, bb.z), 0.f);
    o.w = fmaxf(fmaf(dv, acc.w, bb.w), 0.f);
    ((float4*)h)[v * 32 + lane] = o;
}

// ---------- mean pool (atomic accumulate) ----------
__global__ void k_pool(const float* __restrict__ h, const int* __restrict__ batch,
                       float* __restrict__ psum, float* __restrict__ pcnt) {
    int idx = blockIdx.x * blockDim.x + threadIdx.x;
    if (idx >= N_NODES * CH) return;
    int v = idx >> 7, c = idx & 127;
    int g = batch[v];
    atomicAdd(&psum[g * CH + c], h[idx]);
    if (c == 0) atomicAdd(&pcnt[g], 1.0f);
}

// ---------- classifier head ----------
__global__ __launch_bounds__(128) void k_classify(const float* __restrict__ psum,
                                                  const float* __restrict__ pcnt,
                                                  const float* __restrict__ Wc,
                                                  const float* __restrict__ bc,
                                                  float* __restrict__ out) {
    __shared__ float p[CH];
    int g = blockIdx.x;
    int tid = threadIdx.x;
    float inv = 1.0f / fmaxf(pcnt[g], 1.0f);
    p[tid] = psum[g * CH + tid] * inv;
    __syncthreads();
    if (tid < NOUT) {
        float acc = bc[tid];
        #pragma unroll 4
        for (int k = 0; k < CH; ++k) acc += p[k] * Wc[k * NOUT + tid];
        out[g * NOUT + tid] = acc;
    }
}

extern "C" void kernel_launch(void* const* d_in, const int* in_sizes, int n_in,
                              void* d_out, int out_size, void* d_ws, size_t ws_size,
                              hipStream_t stream) {
    const float* x     = (const float*)d_in[0];
    const int*   ei    = (const int*)d_in[1];   // [2, E]
    const int*   batch = (const int*)d_in[2];
    const float* W1    = (const float*)d_in[3];
    const float* b1    = (const float*)d_in[4];
    const float* W2    = (const float*)d_in[5];
    const float* b2    = (const float*)d_in[6];
    const float* Wc    = (const float*)d_in[7];
    const float* bc    = (const float*)d_in[8];
    float* out = (float*)d_out;

    const int* src = ei;
    const int* dst = ei + N_EDGES;

    // workspace layout
    float* dinv      = (float*)d_ws;                       // N
    int*   cnt       = (int*)(dinv + N_NODES);             // N
    int*   row_start = cnt + N_NODES;                      // N
    int*   fill_pos  = row_start + N_NODES;                // N
    int*   bsum      = fill_pos + N_NODES;                 // 256
    int*   csr_src   = bsum + 256;                         // E
    float* tbuf      = (float*)(csr_src + N_EDGES);        // N*CH
    float* hbuf      = tbuf + (size_t)N_NODES * CH;        // N*CH
    float* psum      = hbuf + (size_t)N_NODES * CH;        // G*CH
    float* pcnt      = psum + NUM_GRAPHS * CH;             // G

    const int NCH = N_NODES * CH;

    // ---- CSR build + norm (once, shared by both convs) ----
    k_zero_int<<<(N_NODES + 255) / 256, 256, 0, stream>>>(cnt, N_NODES);
    k_hist<<<(N_EDGES + 255) / 256, 256, 0, stream>>>(dst, cnt);
    k_scan1<<<N_SCAN_BLOCKS, SCAN_B, 0, stream>>>(cnt, row_start, bsum);
    k_scan2<<<1, SCAN_B, 0, stream>>>(bsum);
    k_scan3<<<N_SCAN_BLOCKS, SCAN_B, 0, stream>>>(row_start, bsum, fill_pos, cnt, dinv);
    k_fill<<<(N_EDGES + 255) / 256, 256, 0, stream>>>(src, dst, fill_pos, csr_src);

    // ---- conv1 ----
    k_gemm128<<<N_NODES / 8, 256, 0, stream>>>(x, W1, tbuf);
    k_gather<<<N_NODES / 8, 256, 0, stream>>>(tbuf, csr_src, row_start, cnt, dinv, b1, hbuf);

    // ---- conv2 ----
    k_gemm128<<<N_NODES / 8, 256, 0, stream>>>(hbuf, W2, tbuf);
    k_gather<<<N_NODES / 8, 256, 0, stream>>>(tbuf, csr_src, row_start, cnt, dinv, b2, hbuf);

    // ---- pool + head ----
    k_zero4<<<((NUM_GRAPHS * CH + NUM_GRAPHS) / 4 + 255) / 256, 256, 0, stream>>>(
        (float4*)psum, (NUM_GRAPHS * CH + NUM_GRAPHS) / 4);
    k_pool<<<(NCH + 255) / 256, 256, 0, stream>>>(hbuf, batch, psum, pcnt);
    k_classify<<<NUM_GRAPHS, 128, 0, stream>>>(psum, pcnt, Wc, bc, out);
}

// Round 3
// 537.531 us; speedup vs baseline: 2.2928x; 1.5355x over previous
//
#include <hip/hip_runtime.h>

#define N_NODES 50000
#define N_EDGES 800000
#define CH 128
#define NOUT 10
#define NUM_GRAPHS 128
#define SCAN_B 256
#define N_SCAN_BLOCKS ((N_NODES + SCAN_B - 1) / SCAN_B)   // 196
#define POOL_CHUNK 50                                      // 50000 = 1000 * 50

// ---------- zero fills ----------
__global__ void k_zero_int(int* p, int n) {
    int i = blockIdx.x * blockDim.x + threadIdx.x;
    if (i < n) p[i] = 0;
}
__global__ void k_zero4(float4* p, int n4) {
    int i = blockIdx.x * blockDim.x + threadIdx.x;
    if (i < n4) p[i] = make_float4(0.f, 0.f, 0.f, 0.f);
}

// ---------- CSR build ----------
__global__ void k_hist(const int* __restrict__ dst, int* __restrict__ cnt) {
    int e = blockIdx.x * blockDim.x + threadIdx.x;
    if (e < N_EDGES) atomicAdd(&cnt[dst[e]], 1);
}

__global__ __launch_bounds__(SCAN_B) void k_scan1(const int* __restrict__ cnt,
                                                  int* __restrict__ row_start,
                                                  int* __restrict__ bsum) {
    __shared__ int s[SCAN_B];
    int tid = threadIdx.x;
    int i = blockIdx.x * SCAN_B + tid;
    int v = (i < N_NODES) ? cnt[i] : 0;
    s[tid] = v;
    __syncthreads();
    for (int off = 1; off < SCAN_B; off <<= 1) {
        int t = (tid >= off) ? s[tid - off] : 0;
        __syncthreads();
        s[tid] += t;
        __syncthreads();
    }
    if (i < N_NODES) row_start[i] = s[tid] - v;
    if (tid == SCAN_B - 1) bsum[blockIdx.x] = s[tid];
}

__global__ __launch_bounds__(SCAN_B) void k_scan2(int* __restrict__ bsum) {
    __shared__ int s[SCAN_B];
    int tid = threadIdx.x;
    int v = (tid < N_SCAN_BLOCKS) ? bsum[tid] : 0;
    s[tid] = v;
    __syncthreads();
    for (int off = 1; off < SCAN_B; off <<= 1) {
        int t = (tid >= off) ? s[tid - off] : 0;
        __syncthreads();
        s[tid] += t;
        __syncthreads();
    }
    if (tid < N_SCAN_BLOCKS) bsum[tid] = s[tid] - v;
}

__global__ __launch_bounds__(SCAN_B) void k_scan3(int* __restrict__ row_start,
                                                  const int* __restrict__ bsum,
                                                  int* __restrict__ fill_pos,
                                                  const int* __restrict__ cnt,
                                                  float* __restrict__ dinv) {
    int i = blockIdx.x * SCAN_B + threadIdx.x;
    if (i < N_NODES) {
        int rs = row_start[i] + bsum[blockIdx.x];
        row_start[i] = rs;
        fill_pos[i] = rs;
        dinv[i] = rsqrtf((float)(cnt[i] + 1));
    }
}

__global__ void k_fill(const int* __restrict__ src, const int* __restrict__ dst,
                       int* __restrict__ fill_pos, int* __restrict__ csr_src) {
    int e = blockIdx.x * blockDim.x + threadIdx.x;
    if (e < N_EDGES) {
        int pos = atomicAdd(&fill_pos[dst[e]], 1);
        csr_src[pos] = src[e];
    }
}

// ---------- dense GEMM: Y[N,128] = X[N,128] @ W[128,128] ----------
__global__ __launch_bounds__(256) void k_gemm128(const float* __restrict__ X,
                                                 const float* __restrict__ W,
                                                 float* __restrict__ Y) {
    __shared__ float xs[8][CH];
    const int tid = threadIdx.x;
    const int r = tid >> 5;
    const int lane = tid & 31;
    const int row0 = blockIdx.x * 8;

    ((float4*)xs)[tid] = ((const float4*)(X + (size_t)row0 * CH))[tid];
    __syncthreads();

    float4 acc = make_float4(0.f, 0.f, 0.f, 0.f);
    const float4* Wv = (const float4*)W;
    #pragma unroll 4
    for (int k = 0; k < CH; ++k) {
        float4 w = Wv[k * 32 + lane];
        float xv = xs[r][k];
        acc.x = fmaf(xv, w.x, acc.x);
        acc.y = fmaf(xv, w.y, acc.y);
        acc.z = fmaf(xv, w.z, acc.z);
        acc.w = fmaf(xv, w.w, acc.w);
    }
    ((float4*)(Y + (size_t)(row0 + r) * CH))[lane] = acc;
}

// ---------- CSR gather-aggregate + bias + relu ----------
__global__ __launch_bounds__(256) void k_gather(const float* __restrict__ t,
                                                const int* __restrict__ csr_src,
                                                const int* __restrict__ row_start,
                                                const int* __restrict__ cnt,
                                                const float* __restrict__ dinv,
                                                const float* __restrict__ b,
                                                float* __restrict__ h) {
    const int g = threadIdx.x >> 5;
    const int lane = threadIdx.x & 31;
    const int v = blockIdx.x * 8 + g;

    const int start = row_start[v];
    const int len = cnt[v];
    const float dv = dinv[v];
    const float4* tv = (const float4*)t;

    float4 self = tv[v * 32 + lane];
    float4 acc;
    acc.x = dv * self.x; acc.y = dv * self.y;
    acc.z = dv * self.z; acc.w = dv * self.w;

    for (int j = 0; j < len; ++j) {
        int u = csr_src[start + j];
        float w = dinv[u];
        float4 tu = tv[u * 32 + lane];
        acc.x = fmaf(w, tu.x, acc.x);
        acc.y = fmaf(w, tu.y, acc.y);
        acc.z = fmaf(w, tu.z, acc.z);
        acc.w = fmaf(w, tu.w, acc.w);
    }

    float4 bb = ((const float4*)b)[lane];
    float4 o;
    o.x = fmaxf(fmaf(dv, acc.x, bb.x), 0.f);
    o.y = fmaxf(fmaf(dv, acc.y, bb.y), 0.f);
    o.z = fmaxf(fmaf(dv, acc.z, bb.z), 0.f);
    o.w = fmaxf(fmaf(dv, acc.w, bb.w), 0.f);
    ((float4*)h)[v * 32 + lane] = o;
}

// ---------- segmented mean pool: batch is SORTED ----------
// block = 128 threads (one per channel) x POOL_CHUNK consecutive nodes.
// Running register accumulate; one atomicAdd per graph-segment per channel.
__global__ __launch_bounds__(128) void k_pool2(const float* __restrict__ h,
                                               const int* __restrict__ batch,
                                               float* __restrict__ psum) {
    const int c = threadIdx.x;
    const int v0 = blockIdx.x * POOL_CHUNK;
    __shared__ int bg[POOL_CHUNK];
    if (c < POOL_CHUNK) bg[c] = batch[v0 + c];
    __syncthreads();

    float acc = 0.f;
    int g = bg[0];
    #pragma unroll 5
    for (int j = 0; j < POOL_CHUNK; ++j) {
        int bgj = bg[j];
        float val = h[(size_t)(v0 + j) * CH + c];   // coalesced 512B
        if (bgj != g) {
            atomicAdd(&psum[g * CH + c], acc);
            acc = 0.f;
            g = bgj;
        }
        acc += val;
    }
    atomicAdd(&psum[g * CH + c], acc);
}

// ---------- per-graph inverse counts via binary search (batch sorted) ----------
__global__ __launch_bounds__(NUM_GRAPHS) void k_counts(const int* __restrict__ batch,
                                                       float* __restrict__ pinv) {
    int g = threadIdx.x;
    int lo = 0, hi = N_NODES;
    while (lo < hi) { int mid = (lo + hi) >> 1; if (batch[mid] < g) lo = mid + 1; else hi = mid; }
    int start = lo;
    lo = 0; hi = N_NODES;
    while (lo < hi) { int mid = (lo + hi) >> 1; if (batch[mid] < g + 1) lo = mid + 1; else hi = mid; }
    int n = lo - start;
    pinv[g] = 1.0f / fmaxf((float)n, 1.0f);
}

// ---------- classifier head ----------
__global__ __launch_bounds__(128) void k_classify(const float* __restrict__ psum,
                                                  const float* __restrict__ pinv,
                                                  const float* __restrict__ Wc,
                                                  const float* __restrict__ bc,
                                                  float* __restrict__ out) {
    __shared__ float p[CH];
    int g = blockIdx.x;
    int tid = threadIdx.x;
    p[tid] = psum[g * CH + tid] * pinv[g];
    __syncthreads();
    if (tid < NOUT) {
        float acc = bc[tid];
        #pragma unroll 4
        for (int k = 0; k < CH; ++k) acc += p[k] * Wc[k * NOUT + tid];
        out[g * NOUT + tid] = acc;
    }
}

extern "C" void kernel_launch(void* const* d_in, const int* in_sizes, int n_in,
                              void* d_out, int out_size, void* d_ws, size_t ws_size,
                              hipStream_t stream) {
    const float* x     = (const float*)d_in[0];
    const int*   ei    = (const int*)d_in[1];
    const int*   batch = (const int*)d_in[2];
    const float* W1    = (const float*)d_in[3];
    const float* b1    = (const float*)d_in[4];
    const float* W2    = (const float*)d_in[5];
    const float* b2    = (const float*)d_in[6];
    const float* Wc    = (const float*)d_in[7];
    const float* bc    = (const float*)d_in[8];
    float* out = (float*)d_out;

    const int* src = ei;
    const int* dst = ei + N_EDGES;

    float* dinv      = (float*)d_ws;                       // N
    int*   cnt       = (int*)(dinv + N_NODES);             // N
    int*   row_start = cnt + N_NODES;                      // N
    int*   fill_pos  = row_start + N_NODES;                // N
    int*   bsum      = fill_pos + N_NODES;                 // 256
    int*   csr_src   = bsum + 256;                         // E
    float* tbuf      = (float*)(csr_src + N_EDGES);        // N*CH
    float* hbuf      = tbuf + (size_t)N_NODES * CH;        // N*CH
    float* psum      = hbuf + (size_t)N_NODES * CH;        // G*CH
    float* pinv      = psum + NUM_GRAPHS * CH;             // G

    // ---- CSR build + norm ----
    k_zero_int<<<(N_NODES + 255) / 256, 256, 0, stream>>>(cnt, N_NODES);
    k_hist<<<(N_EDGES + 255) / 256, 256, 0, stream>>>(dst, cnt);
    k_scan1<<<N_SCAN_BLOCKS, SCAN_B, 0, stream>>>(cnt, row_start, bsum);
    k_scan2<<<1, SCAN_B, 0, stream>>>(bsum);
    k_scan3<<<N_SCAN_BLOCKS, SCAN_B, 0, stream>>>(row_start, bsum, fill_pos, cnt, dinv);
    k_fill<<<(N_EDGES + 255) / 256, 256, 0, stream>>>(src, dst, fill_pos, csr_src);

    // ---- conv1 ----
    k_gemm128<<<N_NODES / 8, 256, 0, stream>>>(x, W1, tbuf);
    k_gather<<<N_NODES / 8, 256, 0, stream>>>(tbuf, csr_src, row_start, cnt, dinv, b1, hbuf);

    // ---- conv2 ----
    k_gemm128<<<N_NODES / 8, 256, 0, stream>>>(hbuf, W2, tbuf);
    k_gather<<<N_NODES / 8, 256, 0, stream>>>(tbuf, csr_src, row_start, cnt, dinv, b2, hbuf);

    // ---- pool + head ----
    k_zero4<<<(NUM_GRAPHS * CH / 4 + 255) / 256, 256, 0, stream>>>(
        (float4*)psum, NUM_GRAPHS * CH / 4);
    k_counts<<<1, NUM_GRAPHS, 0, stream>>>(batch, pinv);
    k_pool2<<<N_NODES / POOL_CHUNK, 128, 0, stream>>>(hbuf, batch, psum);
    k_classify<<<NUM_GRAPHS, 128, 0, stream>>>(psum, pinv, Wc, bc, out);
}

// Round 4
// 378.438 us; speedup vs baseline: 3.2567x; 1.4204x over previous
//
#include <hip/hip_runtime.h>

#define N_NODES 50000
#define N_EDGES 800000
#define CH 128
#define NOUT 10
#define NUM_GRAPHS 128
#define SCAN_B 256
#define N_SCAN_BLOCKS ((N_NODES + SCAN_B - 1) / SCAN_B)   // 196
#define POOL_CHUNK 50
#define GR 64   // gemm rows per block

// ---------- zero fills ----------
__global__ void k_zero_int(int* p, int n) {
    int i = blockIdx.x * blockDim.x + threadIdx.x;
    if (i < n) p[i] = 0;
}
__global__ void k_zero4(float4* p, int n4) {
    int i = blockIdx.x * blockDim.x + threadIdx.x;
    if (i < n4) p[i] = make_float4(0.f, 0.f, 0.f, 0.f);
}

// ---------- CSR build ----------
__global__ void k_hist(const int* __restrict__ dst, int* __restrict__ cnt) {
    int e = blockIdx.x * blockDim.x + threadIdx.x;
    if (e < N_EDGES) atomicAdd(&cnt[dst[e]], 1);
}

__global__ __launch_bounds__(SCAN_B) void k_scan1(const int* __restrict__ cnt,
                                                  int* __restrict__ row_start,
                                                  int* __restrict__ bsum) {
    __shared__ int s[SCAN_B];
    int tid = threadIdx.x;
    int i = blockIdx.x * SCAN_B + tid;
    int v = (i < N_NODES) ? cnt[i] : 0;
    s[tid] = v;
    __syncthreads();
    for (int off = 1; off < SCAN_B; off <<= 1) {
        int t = (tid >= off) ? s[tid - off] : 0;
        __syncthreads();
        s[tid] += t;
        __syncthreads();
    }
    if (i < N_NODES) row_start[i] = s[tid] - v;
    if (tid == SCAN_B - 1) bsum[blockIdx.x] = s[tid];
}

__global__ __launch_bounds__(SCAN_B) void k_scan2(int* __restrict__ bsum) {
    __shared__ int s[SCAN_B];
    int tid = threadIdx.x;
    int v = (tid < N_SCAN_BLOCKS) ? bsum[tid] : 0;
    s[tid] = v;
    __syncthreads();
    for (int off = 1; off < SCAN_B; off <<= 1) {
        int t = (tid >= off) ? s[tid - off] : 0;
        __syncthreads();
        s[tid] += t;
        __syncthreads();
    }
    if (tid < N_SCAN_BLOCKS) bsum[tid] = s[tid] - v;
}

__global__ __launch_bounds__(SCAN_B) void k_scan3(int* __restrict__ row_start,
                                                  const int* __restrict__ bsum,
                                                  int* __restrict__ fill_pos,
                                                  const int* __restrict__ cnt,
                                                  float* __restrict__ dinv) {
    int i = blockIdx.x * SCAN_B + threadIdx.x;
    if (i < N_NODES) {
        int rs = row_start[i] + bsum[blockIdx.x];
        row_start[i] = rs;
        fill_pos[i] = rs;
        dinv[i] = rsqrtf((float)(cnt[i] + 1));
    }
}

__global__ void k_fill(const int* __restrict__ src, const int* __restrict__ dst,
                       int* __restrict__ fill_pos, int* __restrict__ csr_src) {
    int e = blockIdx.x * blockDim.x + threadIdx.x;
    if (e < N_EDGES) {
        int pos = atomicAdd(&fill_pos[dst[e]], 1);
        csr_src[pos] = src[e];
    }
}

// ---------- register-tiled GEMM: Y[N,128] = X[N,128] @ W[128,128] ----------
// 64 rows x 128 cols per block; 256 threads = 8 groups x 32 lanes.
// Thread (g,lane): rows g*8..g*8+7, cols lane*4..lane*4+3 -> 8 float4 acc.
// Per k: 1 global float4 (W) + 8 LDS broadcasts -> 32 FMAs.
__global__ __launch_bounds__(256) void k_gemm_rt(const float* __restrict__ X,
                                                 const float* __restrict__ W,
                                                 float* __restrict__ Y) {
    __shared__ float xs[GR][CH];
    const int tid = threadIdx.x;
    const int lane = tid & 31;
    const int g = tid >> 5;
    const int row0 = blockIdx.x * GR;

    const float4* Xv = (const float4*)X;
    #pragma unroll
    for (int i = 0; i < 8; ++i) {
        int f = tid + i * 256;             // float4 index within tile [0,2048)
        int r = f >> 5;
        float4 val = make_float4(0.f, 0.f, 0.f, 0.f);
        if (row0 + r < N_NODES) val = Xv[(size_t)row0 * 32 + f];
        ((float4*)xs)[f] = val;
    }
    __syncthreads();

    float4 acc[8];
    #pragma unroll
    for (int i = 0; i < 8; ++i) acc[i] = make_float4(0.f, 0.f, 0.f, 0.f);

    const float4* Wv = (const float4*)W;
    #pragma unroll 4
    for (int k = 0; k < CH; ++k) {
        float4 w = Wv[k * 32 + lane];
        #pragma unroll
        for (int i = 0; i < 8; ++i) {
            float xv = xs[g * 8 + i][k];   // 2-way broadcast per wave (free)
            acc[i].x = fmaf(xv, w.x, acc[i].x);
            acc[i].y = fmaf(xv, w.y, acc[i].y);
            acc[i].z = fmaf(xv, w.z, acc[i].z);
            acc[i].w = fmaf(xv, w.w, acc[i].w);
        }
    }

    #pragma unroll
    for (int i = 0; i < 8; ++i) {
        int row = row0 + g * 8 + i;
        if (row < N_NODES) ((float4*)Y)[(size_t)row * 32 + lane] = acc[i];
    }
}

// ---------- gather-aggregate, one wave per node ----------
// Wave preloads <=64 edge ids + dinv coalesced, broadcasts via __shfl,
// 4 independent t-load chains into 4 accumulators.
__global__ __launch_bounds__(256) void k_gather2(const float* __restrict__ t,
                                                 const int* __restrict__ csr_src,
                                                 const int* __restrict__ row_start,
                                                 const int* __restrict__ cnt,
                                                 const float* __restrict__ dinv,
                                                 const float* __restrict__ b,
                                                 float* __restrict__ h) {
    const int wid = threadIdx.x >> 6;
    const int lane = threadIdx.x & 63;
    const int v = blockIdx.x * 4 + wid;      // 12500 * 4 = 50000 exactly

    const int start = row_start[v];
    const int len = cnt[v];
    const float dv = dinv[v];
    const float2* tv = (const float2*)t;

    float2 a0 = {0.f, 0.f}, a1 = {0.f, 0.f}, a2 = {0.f, 0.f}, a3 = {0.f, 0.f};

    for (int base = 0; base < len; base += 64) {
        int m = len - base; if (m > 64) m = 64;
        int u_l = 0;
        if (lane < m) u_l = csr_src[start + base + lane];   // coalesced
        float w_l = dinv[u_l];                               // one scattered 4B/lane
        int j = 0;
        for (; j + 3 < m; j += 4) {
            int u0 = __shfl(u_l, j),     u1 = __shfl(u_l, j + 1);
            int u2 = __shfl(u_l, j + 2), u3 = __shfl(u_l, j + 3);
            float w0 = __shfl(w_l, j),     w1 = __shfl(w_l, j + 1);
            float w2 = __shfl(w_l, j + 2), w3 = __shfl(w_l, j + 3);
            float2 t0 = tv[(size_t)u0 * 64 + lane];
            float2 t1 = tv[(size_t)u1 * 64 + lane];
            float2 t2 = tv[(size_t)u2 * 64 + lane];
            float2 t3 = tv[(size_t)u3 * 64 + lane];
            a0.x = fmaf(w0, t0.x, a0.x); a0.y = fmaf(w0, t0.y, a0.y);
            a1.x = fmaf(w1, t1.x, a1.x); a1.y = fmaf(w1, t1.y, a1.y);
            a2.x = fmaf(w2, t2.x, a2.x); a2.y = fmaf(w2, t2.y, a2.y);
            a3.x = fmaf(w3, t3.x, a3.x); a3.y = fmaf(w3, t3.y, a3.y);
        }
        for (; j < m; ++j) {
            int u = __shfl(u_l, j);
            float w = __shfl(w_l, j);
            float2 tt = tv[(size_t)u * 64 + lane];
            a0.x = fmaf(w, tt.x, a0.x); a0.y = fmaf(w, tt.y, a0.y);
        }
    }

    float2 self = tv[(size_t)v * 64 + lane];
    float sx = a0.x + a1.x + a2.x + a3.x + dv * self.x;
    float sy = a0.y + a1.y + a2.y + a3.y + dv * self.y;
    float2 bb = ((const float2*)b)[lane];
    float2 o;
    o.x = fmaxf(fmaf(dv, sx, bb.x), 0.f);
    o.y = fmaxf(fmaf(dv, sy, bb.y), 0.f);
    ((float2*)h)[(size_t)v * 64 + lane] = o;
}

// ---------- segmented mean pool (batch sorted) ----------
__global__ __launch_bounds__(128) void k_pool2(const float* __restrict__ h,
                                               const int* __restrict__ batch,
                                               float* __restrict__ psum) {
    const int c = threadIdx.x;
    const int v0 = blockIdx.x * POOL_CHUNK;
    __shared__ int bg[POOL_CHUNK];
    if (c < POOL_CHUNK) bg[c] = batch[v0 + c];
    __syncthreads();

    float acc = 0.f;
    int g = bg[0];
    #pragma unroll 5
    for (int j = 0; j < POOL_CHUNK; ++j) {
        int bgj = bg[j];
        float val = h[(size_t)(v0 + j) * CH + c];
        if (bgj != g) {
            atomicAdd(&psum[g * CH + c], acc);
            acc = 0.f;
            g = bgj;
        }
        acc += val;
    }
    atomicAdd(&psum[g * CH + c], acc);
}

// ---------- per-graph inverse counts (batch sorted) ----------
__global__ __launch_bounds__(NUM_GRAPHS) void k_counts(const int* __restrict__ batch,
                                                       float* __restrict__ pinv) {
    int g = threadIdx.x;
    int lo = 0, hi = N_NODES;
    while (lo < hi) { int mid = (lo + hi) >> 1; if (batch[mid] < g) lo = mid + 1; else hi = mid; }
    int start = lo;
    lo = 0; hi = N_NODES;
    while (lo < hi) { int mid = (lo + hi) >> 1; if (batch[mid] < g + 1) lo = mid + 1; else hi = mid; }
    int n = lo - start;
    pinv[g] = 1.0f / fmaxf((float)n, 1.0f);
}

// ---------- classifier head ----------
__global__ __launch_bounds__(128) void k_classify(const float* __restrict__ psum,
                                                  const float* __restrict__ pinv,
                                                  const float* __restrict__ Wc,
                                                  const float* __restrict__ bc,
                                                  float* __restrict__ out) {
    __shared__ float p[CH];
    int g = blockIdx.x;
    int tid = threadIdx.x;
    p[tid] = psum[g * CH + tid] * pinv[g];
    __syncthreads();
    if (tid < NOUT) {
        float acc = bc[tid];
        #pragma unroll 4
        for (int k = 0; k < CH; ++k) acc += p[k] * Wc[k * NOUT + tid];
        out[g * NOUT + tid] = acc;
    }
}

extern "C" void kernel_launch(void* const* d_in, const int* in_sizes, int n_in,
                              void* d_out, int out_size, void* d_ws, size_t ws_size,
                              hipStream_t stream) {
    const float* x     = (const float*)d_in[0];
    const int*   ei    = (const int*)d_in[1];
    const int*   batch = (const int*)d_in[2];
    const float* W1    = (const float*)d_in[3];
    const float* b1    = (const float*)d_in[4];
    const float* W2    = (const float*)d_in[5];
    const float* b2    = (const float*)d_in[6];
    const float* Wc    = (const float*)d_in[7];
    const float* bc    = (const float*)d_in[8];
    float* out = (float*)d_out;

    const int* src = ei;
    const int* dst = ei + N_EDGES;

    float* dinv      = (float*)d_ws;                       // N
    int*   cnt       = (int*)(dinv + N_NODES);             // N
    int*   row_start = cnt + N_NODES;                      // N
    int*   fill_pos  = row_start + N_NODES;                // N
    int*   bsum      = fill_pos + N_NODES;                 // 256
    int*   csr_src   = bsum + 256;                         // E
    float* tbuf      = (float*)(csr_src + N_EDGES);        // N*CH
    float* hbuf      = tbuf + (size_t)N_NODES * CH;        // N*CH
    float* psum      = hbuf + (size_t)N_NODES * CH;        // G*CH
    float* pinv      = psum + NUM_GRAPHS * CH;             // G

    // ---- CSR build + norm ----
    k_zero_int<<<(N_NODES + 255) / 256, 256, 0, stream>>>(cnt, N_NODES);
    k_hist<<<(N_EDGES + 255) / 256, 256, 0, stream>>>(dst, cnt);
    k_scan1<<<N_SCAN_BLOCKS, SCAN_B, 0, stream>>>(cnt, row_start, bsum);
    k_scan2<<<1, SCAN_B, 0, stream>>>(bsum);
    k_scan3<<<N_SCAN_BLOCKS, SCAN_B, 0, stream>>>(row_start, bsum, fill_pos, cnt, dinv);
    k_fill<<<(N_EDGES + 255) / 256, 256, 0, stream>>>(src, dst, fill_pos, csr_src);

    // ---- conv1 ----
    k_gemm_rt<<<(N_NODES + GR - 1) / GR, 256, 0, stream>>>(x, W1, tbuf);
    k_gather2<<<N_NODES / 4, 256, 0, stream>>>(tbuf, csr_src, row_start, cnt, dinv, b1, hbuf);

    // ---- conv2 ----
    k_gemm_rt<<<(N_NODES + GR - 1) / GR, 256, 0, stream>>>(hbuf, W2, tbuf);
    k_gather2<<<N_NODES / 4, 256, 0, stream>>>(tbuf, csr_src, row_start, cnt, dinv, b2, hbuf);

    // ---- pool + head ----
    k_zero4<<<(NUM_GRAPHS * CH / 4 + 255) / 256, 256, 0, stream>>>(
        (float4*)psum, NUM_GRAPHS * CH / 4);
    k_counts<<<1, NUM_GRAPHS, 0, stream>>>(batch, pinv);
    k_pool2<<<N_NODES / POOL_CHUNK, 128, 0, stream>>>(hbuf, batch, psum);
    k_classify<<<NUM_GRAPHS, 128, 0, stream>>>(psum, pinv, Wc, bc, out);
}